// Round 11
// baseline (604.960 us; speedup 1.0000x reference)
//
#include <hip/hip_runtime.h>

// RG-LRU fused kernel set for MI355X (gfx950)
// B=4, T=4096, D=1024
// R11 = R10 with BKT 64->32: BUFB 32KB, double-buffer 64KB -> 2 blocks/CU
//   co-resident (was 1). Per K-tile: 2 phases {16 MFMA + reads}, 4 gload16.
//   ONE barrier per tile (P0): stage-after-barrier makes buffer reuse safe
//   (nb's readers finished before the barrier); vmcnt(0) at P0 is exact.
//   Swizzle: slot = lg ^ ((row>>1)&3) on 64B rows (R3-verified, 0 conflicts).

#define B_ 4
#define T_ 4096
#define D_ 1024
#define BT_ (B_ * T_)          // 16384
#define NC_ 64                 // chunks over T (chunk = 64 steps)

#define BMR 256                // M rows per block
#define BNC 128                // d cols per block
#define BKT 32                 // K per tile
#define NT_ (D_ / BKT)         // 32 K-tiles
#define BUFB 32768             // bytes per LDS buffer (A 16K + B 16K)

typedef float v4f __attribute__((ext_vector_type(4)));
typedef __bf16 v8bf __attribute__((ext_vector_type(8)));
typedef unsigned int u32;

__device__ inline unsigned short f2bf(float f) {
    unsigned int u = __float_as_uint(f);
    u += 0x7FFFu + ((u >> 16) & 1u);   // RNE
    return (unsigned short)(u >> 16);
}
__device__ inline ushort4 f2bf4(float4 v) {
    return make_ushort4(f2bf(v.x), f2bf(v.y), f2bf(v.z), f2bf(v.w));
}
__device__ inline u32 pack2(float p, float h) {
    _Float16 ph = (_Float16)p, hh = (_Float16)h;
    unsigned short pu, hu;
    __builtin_memcpy(&pu, &ph, 2);
    __builtin_memcpy(&hu, &hh, 2);
    return ((u32)hu << 16) | pu;
}
__device__ inline float unp_lo(u32 v) {
    unsigned short u = (unsigned short)(v & 0xffffu);
    _Float16 h; __builtin_memcpy(&h, &u, 2); return (float)h;
}
__device__ inline float unp_hi(u32 v) {
    unsigned short u = (unsigned short)(v >> 16);
    _Float16 h; __builtin_memcpy(&h, &u, 2); return (float)h;
}
__device__ inline float bf2f(unsigned short u) {
    return __uint_as_float((u32)u << 16);
}
__device__ inline void gload16(const void* g, void* l) {
    __builtin_amdgcn_global_load_lds(
        (const __attribute__((address_space(1))) u32*)g,
        (__attribute__((address_space(3))) u32*)l, 16, 0, 0);
}

// ---------------------------------------------------------------- prep
__global__ void prep_kernel(const float4* __restrict__ x4,
                            const float4* __restrict__ wr4,
                            const float4* __restrict__ wi4,
                            const float* __restrict__ lam,
                            ushort4* __restrict__ xb4,
                            ushort4* __restrict__ wrb4,
                            ushort4* __restrict__ wib4,
                            float* __restrict__ decay) {
    const int n = gridDim.x * blockDim.x;
    const int tid = blockIdx.x * blockDim.x + threadIdx.x;
    const int nx4 = (BT_ * D_) / 4;
    const int nw4 = (D_ * D_) / 4;
    for (int i = tid; i < nx4; i += n) xb4[i] = f2bf4(x4[i]);
    for (int i = tid; i < nw4; i += n) {
        wrb4[i] = f2bf4(wr4[i]);
        wib4[i] = f2bf4(wi4[i]);
    }
    for (int i = tid; i < D_; i += n) {
        float sp = log1pf(expf(lam[i]));
        decay[i] = 8.0f * sp;
    }
}

// ---------------------------------------------------------------- gemm + gates + prefix
// LDS buffer: A region [row 0..255][slot 0..3 (16B)] (16KB, 64B rows), then
// B region rows 0..255 = [Wr cols 0..127 | Wi cols 0..127] (16KB).
// Swizzle: LDS slot s of row r holds global k-slot (s ^ ((r>>1)&3)).
__global__ __launch_bounds__(512, 4) void gemm_gates(
    const unsigned short* __restrict__ xb,
    const unsigned short* __restrict__ wrb,
    const unsigned short* __restrict__ wib,
    const float* __restrict__ br,
    const float* __restrict__ bi,
    const float* __restrict__ decay,
    u32* __restrict__ ag,
    float* __restrict__ Pg,
    float* __restrict__ Hg) {
    __shared__ __align__(16) char lds[2 * BUFB];   // 64 KB -> 2 blocks/CU

    const int tid = threadIdx.x;
    const int lane = tid & 63;
    const int wave = tid >> 6;      // 0..7
    const int wr = wave >> 2;       // 0..1 (128-row half)
    const int wc = wave & 3;        // 0..3 (32-col strip)
    const int lr = lane & 15;
    const int lg = lane >> 4;
    const int rowbase = blockIdx.x * BMR;
    const int colbase = blockIdx.y * BNC;

    // staging map: one gload16 covers 8KB = 128 rows x 64B
    const int srow = tid >> 2;                          // 0..127
    const int kslot = (tid & 3) ^ ((srow >> 1) & 3);    // pre-swizzled k slot

    const unsigned short* gAq[2];
    gAq[0] = xb + (size_t)(rowbase + srow) * D_ + kslot * 8;
    gAq[1] = xb + (size_t)(rowbase + 128 + srow) * D_ + kslot * 8;
    const unsigned short* gBq[2];
    gBq[0] = wrb + (size_t)(colbase + srow) * D_ + kslot * 8;
    gBq[1] = wib + (size_t)(colbase + srow) * D_ + kslot * 8;

#define STG_A(nb, q, kel) gload16(gAq[q] + (kel), lds + (nb) * BUFB + (q) * 8192 + wave * 1024)
#define STG_B(nb, q, kel) gload16(gBq[q] + (kel), lds + (nb) * BUFB + 16384 + (q) * 8192 + wave * 1024)

    v4f ar[8][2], ai[8][2];
#pragma unroll
    for (int mi = 0; mi < 8; ++mi)
#pragma unroll
        for (int nf = 0; nf < 2; ++nf)
#pragma unroll
            for (int j = 0; j < 4; ++j) { ar[mi][nf][j] = 0.0f; ai[mi][nf][j] = 0.0f; }

    v8bf cbr[2], cbi[2];   // B fragments, persist MH0 -> MH1

    // ---- prologue: stage tile 0 into buf 0 (drained by P0(0)'s vmcnt)
    STG_A(0, 0, 0); STG_A(0, 1, 0);
    STG_B(0, 0, 0); STG_B(0, 1, 0);

#define READS(lb, MH, DO_B)                                                     \
    do {                                                                        \
        if (DO_B) {                                                             \
            _Pragma("unroll")                                                   \
            for (int nf = 0; nf < 2; ++nf) {                                    \
                const int cc = wc * 32 + nf * 16 + lr;        /* 0..127 */      \
                cbr[nf] = *(const v8bf*)((lb) + 16384 + cc * 64 +               \
                                         ((lg ^ ((cc >> 1) & 3)) * 16));        \
                const int ci = 128 + cc;                                        \
                cbi[nf] = *(const v8bf*)((lb) + 16384 + ci * 64 +               \
                                         ((lg ^ ((ci >> 1) & 3)) * 16));        \
            }                                                                   \
        }                                                                       \
        _Pragma("unroll")                                                       \
        for (int m4 = 0; m4 < 4; ++m4) {                                        \
            const int row = wr * 128 + ((MH) * 4 + m4) * 16 + lr;               \
            af[m4] = *(const v8bf*)((lb) + row * 64 +                           \
                                    ((lg ^ ((row >> 1) & 3)) * 16));            \
        }                                                                       \
    } while (0)

#define MFMAS(MH)                                                               \
    do {                                                                        \
        __builtin_amdgcn_s_setprio(1);                                          \
        _Pragma("unroll")                                                       \
        for (int m4 = 0; m4 < 4; ++m4)                                          \
            _Pragma("unroll")                                                   \
            for (int nf = 0; nf < 2; ++nf) {                                    \
                ar[(MH) * 4 + m4][nf] = __builtin_amdgcn_mfma_f32_16x16x32_bf16( \
                    af[m4], cbr[nf], ar[(MH) * 4 + m4][nf], 0, 0, 0);           \
                ai[(MH) * 4 + m4][nf] = __builtin_amdgcn_mfma_f32_16x16x32_bf16( \
                    af[m4], cbi[nf], ai[(MH) * 4 + m4][nf], 0, 0, 0);           \
            }                                                                   \
        __builtin_amdgcn_s_setprio(0);                                          \
        __builtin_amdgcn_sched_barrier(0);                                      \
    } while (0)

    for (int t = 0; t < NT_; ++t) {
        const int sw = t & 1;
        const int nb = sw ^ 1;
        const char* lb = lds + sw * BUFB;
        const int knext = (t + 1) * BKT;
        const bool more = (t + 1 < NT_);

        // ---- P0: drain tile t (exact), barrier, stage A(t+1), reads, MFMA
        __builtin_amdgcn_sched_barrier(0);
        asm volatile("s_waitcnt vmcnt(0)");
        __builtin_amdgcn_s_barrier();
        if (more) { STG_A(nb, 0, knext); STG_A(nb, 1, knext); }
        __builtin_amdgcn_sched_barrier(0);
        {
            v8bf af[4];
            READS(lb, 0, 1);
            MFMAS(0);
        }
        // ---- P1: stage B(t+1), reads MH1, MFMA (no barrier needed)
        if (more) { STG_B(nb, 0, knext); STG_B(nb, 1, knext); }
        __builtin_amdgcn_sched_barrier(0);
        {
            v8bf af[4];
            READS(lb, 1, 0);
            MFMAS(1);
        }
    }
#undef READS
#undef MFMAS
#undef STG_A
#undef STG_B

    // ---- epilogue: gates + in-register chunk prefix scan ----
#pragma unroll
    for (int nf = 0; nf < 2; ++nf) {
        const int gcol = colbase + wc * 32 + nf * 16 + lr;
        const float brv = br[gcol];
        const float biv = bi[gcol];
        const float dec = decay[gcol];
#pragma unroll
        for (int half = 0; half < 2; ++half) {
            float Sp = 1.0f, Sh = 0.0f;
#pragma unroll
            for (int m4 = 0; m4 < 4; ++m4) {
                const int mi = half * 4 + m4;
                float av[4], gv[4];
#pragma unroll
                for (int rr = 0; rr < 4; ++rr) {
                    const int grow = rowbase + wr * 128 + mi * 16 + lg * 4 + rr;
                    const float zr = ar[mi][nf][rr] + brv;
                    const float zi = ai[mi][nf][rr] + biv;
                    const float rg = 1.0f / (1.0f + __expf(-zr));
                    const float ig = 1.0f / (1.0f + __expf(-zi));
                    av[rr] = __expf(-dec * rg);
                    const float sc = sqrtf(fmaxf(1.0f - av[rr] * av[rr], 0.0f));
                    gv[rr] = sc * (ig * bf2f(xb[(size_t)grow * D_ + gcol]));
                }
                // lane-local compose over 4 rows
                float lp = (av[0] * av[1]) * (av[2] * av[3]);
                float lh = gv[0];
                lh = av[1] * lh + gv[1];
                lh = av[2] * lh + gv[2];
                lh = av[3] * lh + gv[3];
                // ordered inclusive scan across lg (groups of 16 lanes)
                float cp = lp, ch = lh;
                {
                    const float pp = __shfl_up(cp, 16, 64);
                    const float ph = __shfl_up(ch, 16, 64);
                    if (lg >= 1) { ch = cp * ph + ch; cp = pp * cp; }
                }
                {
                    const float pp = __shfl_up(cp, 32, 64);
                    const float ph = __shfl_up(ch, 32, 64);
                    if (lg >= 2) { ch = cp * ph + ch; cp = pp * cp; }
                }
                // exclusive across lg
                float ep = __shfl_up(cp, 16, 64);
                float eh = __shfl_up(ch, 16, 64);
                if (lg == 0) { ep = 1.0f; eh = 0.0f; }
                // state before my 4 rows
                float wp = Sp * ep;
                float wh = ep * Sh + eh;
#pragma unroll
                for (int rr = 0; rr < 4; ++rr) {
                    wh = av[rr] * wh + gv[rr];
                    wp = wp * av[rr];
                    const int grow = rowbase + wr * 128 + mi * 16 + lg * 4 + rr;
                    ag[(size_t)grow * D_ + gcol] = pack2(wp, wh);
                }
                // advance S by the full 16-row block (inclusive at lg==3)
                const float fp3 = __shfl(cp, 48 + lr, 64);
                const float fh3 = __shfl(ch, 48 + lr, 64);
                Sh = fp3 * Sh + fh3;
                Sp = Sp * fp3;
            }
            if (lg == 0) {
                const int gc = (rowbase >> 6) + wr * 2 + half;   // global chunk id
                Pg[(size_t)gc * D_ + gcol] = Sp;
                Hg[(size_t)gc * D_ + gcol] = Sh;
            }
        }
    }
}

// ---------------------------------------------------------------- combine
__global__ __launch_bounds__(256) void combine(const float* __restrict__ P,
                                               const float* __restrict__ H,
                                               const float* __restrict__ h0,
                                               float* __restrict__ hstart,
                                               float* __restrict__ hT) {
    const int idx = blockIdx.x * 256 + threadIdx.x;   // [0, B*D)
    const int d = idx & (D_ - 1);
    const int b = idx >> 10;
    float h = h0[b * D_ + d];
    for (int c = 0; c < NC_; ++c) {
        const int o = (b * NC_ + c) * D_ + d;
        hstart[o] = h;
        h = P[o] * h + H[o];
    }
    hT[b * D_ + d] = h;
}

// ---------------------------------------------------------------- scan2: pointwise fixup
__global__ __launch_bounds__(256) void scan2(const uint4* __restrict__ ag4,
                                             const float4* __restrict__ hs4,
                                             float4* __restrict__ out4) {
    const int n = (BT_ * D_) / 4;
    const int stride = gridDim.x * 256;
    for (int i = blockIdx.x * 256 + threadIdx.x; i < n; i += stride) {
        const int d4 = i & (D_ / 4 - 1);     // 0..255
        const int row = i >> 8;               // b*T + t
        const int b = row >> 12;
        const int c = (row & (T_ - 1)) >> 6;
        const float4 hs = hs4[(size_t)(b * NC_ + c) * (D_ / 4) + d4];
        const uint4 v = ag4[i];
        float4 o;
        o.x = unp_hi(v.x) + unp_lo(v.x) * hs.x;
        o.y = unp_hi(v.y) + unp_lo(v.y) * hs.y;
        o.z = unp_hi(v.z) + unp_lo(v.z) * hs.z;
        o.w = unp_hi(v.w) + unp_lo(v.w) * hs.w;
        out4[i] = o;
    }
}

// ---------------------------------------------------------------- launch
extern "C" void kernel_launch(void* const* d_in, const int* in_sizes, int n_in,
                              void* d_out, int out_size, void* d_ws, size_t ws_size,
                              hipStream_t stream) {
    const float* x   = (const float*)d_in[0];
    const float* h0  = (const float*)d_in[1];
    const float* Wr  = (const float*)d_in[2];
    const float* br  = (const float*)d_in[3];
    const float* Wi  = (const float*)d_in[4];
    const float* bi  = (const float*)d_in[5];
    const float* lam = (const float*)d_in[6];
    float* out = (float*)d_out;

    char* ws = (char*)d_ws;
    unsigned short* xb  = (unsigned short*)ws; ws += (size_t)BT_ * D_ * 2;   // 33.5 MB
    unsigned short* wrb = (unsigned short*)ws; ws += (size_t)D_ * D_ * 2;    //  2 MB
    unsigned short* wib = (unsigned short*)ws; ws += (size_t)D_ * D_ * 2;    //  2 MB
    float* decay  = (float*)ws;  ws += (size_t)D_ * 4;                       //  4 KB
    u32* ag       = (u32*)ws;    ws += (size_t)BT_ * D_ * 4;                 // 67 MB
    float* Pg     = (float*)ws;  ws += (size_t)B_ * NC_ * D_ * 4;            //  1 MB
    float* Hg     = (float*)ws;  ws += (size_t)B_ * NC_ * D_ * 4;            //  1 MB
    float* hstart = (float*)ws;                                              //  1 MB

    prep_kernel<<<2048, 256, 0, stream>>>(
        (const float4*)x, (const float4*)Wr, (const float4*)Wi, lam,
        (ushort4*)xb, (ushort4*)wrb, (ushort4*)wib, decay);

    gemm_gates<<<dim3(BT_ / BMR, D_ / BNC), 512, 0, stream>>>(
        xb, wrb, wib, br, bi, decay, ag, Pg, Hg);

    combine<<<(B_ * D_) / 256, 256, 0, stream>>>(Pg, Hg, h0, hstart, out + (size_t)BT_ * D_);

    scan2<<<2048, 256, 0, stream>>>((const uint4*)ag, (const float4*)hstart, (float4*)out);
}

// Round 12
// 138.471 us; speedup vs baseline: 4.3689x; 4.3689x over previous
//
#include <hip/hip_runtime.h>

// RG-LRU fused kernel set for MI355X (gfx950)
// B=4, T=4096, D=1024
// R12 = R10 (best: 138.9us total, gemm 97.6us) + XCD-aware block swizzle:
//   flat grid 512; by=(bid>>3)&7, bx=(bid&7)*8+(bid>>6)  (bijective 8x8x8).
//   XCD k (= bid%8 round-robin) hosts row-tiles 8k..8k+7 -> co-resident A
//   working set 2MB (was 16MB) + W 4MB -> A staging becomes L2-hit.
// K-loop/barrier/epilogue identical to R10.

#define B_ 4
#define T_ 4096
#define D_ 1024
#define BT_ (B_ * T_)          // 16384
#define NC_ 64                 // chunks over T (chunk = 64 steps)

#define BMR 256                // M rows per block
#define BNC 128                // d cols per block
#define BKT 64                 // K per tile
#define NT_ (D_ / BKT)         // 16 K-tiles
#define BUFB 65536             // bytes per LDS buffer (A 32K + B 32K)

typedef float v4f __attribute__((ext_vector_type(4)));
typedef __bf16 v8bf __attribute__((ext_vector_type(8)));
typedef unsigned int u32;

__device__ inline unsigned short f2bf(float f) {
    unsigned int u = __float_as_uint(f);
    u += 0x7FFFu + ((u >> 16) & 1u);   // RNE
    return (unsigned short)(u >> 16);
}
__device__ inline ushort4 f2bf4(float4 v) {
    return make_ushort4(f2bf(v.x), f2bf(v.y), f2bf(v.z), f2bf(v.w));
}
__device__ inline u32 pack2(float p, float h) {
    _Float16 ph = (_Float16)p, hh = (_Float16)h;
    unsigned short pu, hu;
    __builtin_memcpy(&pu, &ph, 2);
    __builtin_memcpy(&hu, &hh, 2);
    return ((u32)hu << 16) | pu;
}
__device__ inline float unp_lo(u32 v) {
    unsigned short u = (unsigned short)(v & 0xffffu);
    _Float16 h; __builtin_memcpy(&h, &u, 2); return (float)h;
}
__device__ inline float unp_hi(u32 v) {
    unsigned short u = (unsigned short)(v >> 16);
    _Float16 h; __builtin_memcpy(&h, &u, 2); return (float)h;
}
__device__ inline float bf2f(unsigned short u) {
    return __uint_as_float((u32)u << 16);
}
__device__ inline void gload16(const void* g, void* l) {
    __builtin_amdgcn_global_load_lds(
        (const __attribute__((address_space(1))) u32*)g,
        (__attribute__((address_space(3))) u32*)l, 16, 0, 0);
}

// ---------------------------------------------------------------- prep
__global__ void prep_kernel(const float4* __restrict__ x4,
                            const float4* __restrict__ wr4,
                            const float4* __restrict__ wi4,
                            const float* __restrict__ lam,
                            ushort4* __restrict__ xb4,
                            ushort4* __restrict__ wrb4,
                            ushort4* __restrict__ wib4,
                            float* __restrict__ decay) {
    const int n = gridDim.x * blockDim.x;
    const int tid = blockIdx.x * blockDim.x + threadIdx.x;
    const int nx4 = (BT_ * D_) / 4;
    const int nw4 = (D_ * D_) / 4;
    for (int i = tid; i < nx4; i += n) xb4[i] = f2bf4(x4[i]);
    for (int i = tid; i < nw4; i += n) {
        wrb4[i] = f2bf4(wr4[i]);
        wib4[i] = f2bf4(wi4[i]);
    }
    for (int i = tid; i < D_; i += n) {
        float sp = log1pf(expf(lam[i]));
        decay[i] = 8.0f * sp;
    }
}

// ---------------------------------------------------------------- gemm + gates + prefix
__global__ __launch_bounds__(512, 2) void gemm_gates(
    const unsigned short* __restrict__ xb,
    const unsigned short* __restrict__ wrb,
    const unsigned short* __restrict__ wib,
    const float* __restrict__ br,
    const float* __restrict__ bi,
    const float* __restrict__ decay,
    u32* __restrict__ ag,
    float* __restrict__ Pg,
    float* __restrict__ Hg) {
    __shared__ __align__(16) char lds[2 * BUFB];   // 128 KB

    const int tid = threadIdx.x;
    const int lane = tid & 63;
    const int wave = tid >> 6;      // 0..7
    const int wr = wave >> 2;       // 0..1
    const int wc = wave & 3;        // 0..3
    const int lr = lane & 15;
    const int lg = lane >> 4;

    // XCD-aware swizzle: bijective 8x8x8 decode of the flat 512-block grid.
    // XCD = bid%8 hosts bx in {8k..8k+7}: co-resident A set 2MB -> L2-hit.
    const int bid = blockIdx.x;
    const int by = (bid >> 3) & 7;                 // col-tile 0..7
    const int bx = (bid & 7) * 8 + (bid >> 6);     // row-tile 0..63
    const int rowbase = bx * BMR;
    const int colbase = by * BNC;

    // staging map: thread covers one 16B piece per gload16 issue
    const int srow = tid >> 3;                    // 0..63 within quarter
    const int kslot = (tid & 7) ^ (srow & 7);     // pre-swizzled global slot

    const unsigned short* gAq[4];
#pragma unroll
    for (int q = 0; q < 4; ++q)
        gAq[q] = xb + (size_t)(rowbase + q * 64 + srow) * D_ + kslot * 8;
    const unsigned short* gBq[4];
    gBq[0] = wrb + (size_t)(colbase + srow) * D_ + kslot * 8;
    gBq[1] = wib + (size_t)(colbase + srow) * D_ + kslot * 8;
    gBq[2] = wrb + (size_t)(colbase + 64 + srow) * D_ + kslot * 8;
    gBq[3] = wib + (size_t)(colbase + 64 + srow) * D_ + kslot * 8;

#define STG_A(nb, q, kel) gload16(gAq[q] + (kel), lds + (nb) * BUFB + (q) * 8192 + wave * 1024)
#define STG_B(nb, q, kel) gload16(gBq[q] + (kel), lds + (nb) * BUFB + 32768 + (q) * 8192 + wave * 1024)

    const int bo = (wc & 1) * 32;       // within-strip col offset
    const int bstrip = wc >> 1;         // d-strip (0: d0..63, 1: d64..127)

    v4f ar[8][2], ai[8][2];
#pragma unroll
    for (int mi = 0; mi < 8; ++mi)
#pragma unroll
        for (int nf = 0; nf < 2; ++nf)
#pragma unroll
            for (int j = 0; j < 4; ++j) { ar[mi][nf][j] = 0.0f; ai[mi][nf][j] = 0.0f; }

    v8bf cbr[2], cbi[2];   // B fragments, persist MH0 -> MH1

    // ---- prologue: stage tile 0 into buf 0, full drain
    STG_A(0, 0, 0); STG_A(0, 1, 0); STG_A(0, 2, 0); STG_A(0, 3, 0);
    STG_B(0, 0, 0); STG_B(0, 1, 0); STG_B(0, 2, 0); STG_B(0, 3, 0);
    __builtin_amdgcn_sched_barrier(0);
    asm volatile("s_waitcnt vmcnt(0)");
    __builtin_amdgcn_s_barrier();

    // phase = { ds_reads; WAIT; s_barrier; STAGE; setprio MFMA setprio }
#define PHASE(lb, KS, MH, WAITCODE, STAGECODE)                                  \
    do {                                                                        \
        if ((MH) == 0) {                                                        \
            _Pragma("unroll")                                                   \
            for (int nf = 0; nf < 2; ++nf) {                                    \
                const int brr = bstrip * 128 + bo + nf * 16 + lr;               \
                cbr[nf] = *(const v8bf*)((lb) + 32768 + brr * 128 +             \
                                         (((KS) * 4 + lg) ^ (brr & 7)) * 16);   \
                const int bri = brr + 64;                                       \
                cbi[nf] = *(const v8bf*)((lb) + 32768 + bri * 128 +             \
                                         (((KS) * 4 + lg) ^ (bri & 7)) * 16);   \
            }                                                                   \
        }                                                                       \
        v8bf af[4];                                                             \
        _Pragma("unroll")                                                       \
        for (int m4 = 0; m4 < 4; ++m4) {                                        \
            const int row = wr * 128 + ((MH) * 4 + m4) * 16 + lr;               \
            af[m4] = *(const v8bf*)((lb) + row * 128 +                          \
                                    (((KS) * 4 + lg) ^ (row & 7)) * 16);        \
        }                                                                       \
        __builtin_amdgcn_sched_barrier(0);                                      \
        WAITCODE;                                                               \
        __builtin_amdgcn_s_barrier();                                           \
        STAGECODE;                                                              \
        __builtin_amdgcn_s_setprio(1);                                          \
        _Pragma("unroll")                                                       \
        for (int m4 = 0; m4 < 4; ++m4)                                          \
            _Pragma("unroll")                                                   \
            for (int nf = 0; nf < 2; ++nf) {                                    \
                ar[(MH) * 4 + m4][nf] = __builtin_amdgcn_mfma_f32_16x16x32_bf16( \
                    af[m4], cbr[nf], ar[(MH) * 4 + m4][nf], 0, 0, 0);           \
                ai[(MH) * 4 + m4][nf] = __builtin_amdgcn_mfma_f32_16x16x32_bf16( \
                    af[m4], cbi[nf], ai[(MH) * 4 + m4][nf], 0, 0, 0);           \
            }                                                                   \
        __builtin_amdgcn_s_setprio(0);                                          \
        __builtin_amdgcn_sched_barrier(0);                                      \
    } while (0)

    for (int t = 0; t < NT_; ++t) {
        const int sw = t & 1;
        const int nb = sw ^ 1;
        const char* lb = lds + sw * BUFB;
        const int knext = (t + 1) * BKT;
        const bool more = (t + 1 < NT_);

        // P0: reads B(ks0)+A02; vmcnt(0) drains A13(t) [issued t-1 P2, gap 2];
        //     barrier; stage B01,B23(t+1)
        PHASE(lb, 0, 0,
              { asm volatile("s_waitcnt vmcnt(0)"); },
              if (more) {
                  STG_B(nb, 0, knext); STG_B(nb, 1, knext);
                  STG_B(nb, 2, knext); STG_B(nb, 3, knext);
              });
        // P1: reads A13; barrier; stage A02(t+1)
        PHASE(lb, 0, 1, {},
              if (more) { STG_A(nb, 0, knext); STG_A(nb, 2, knext); });
        // P2: reads B(ks1)+A02; barrier; stage A13(t+1)
        PHASE(lb, 1, 0, {},
              if (more) { STG_A(nb, 1, knext); STG_A(nb, 3, knext); });
        // P3: reads A13; vmcnt(2) leaves A13(t+1), drains B+A02(t+1) [gap >=2]
        PHASE(lb, 1, 1,
              {
                  if (more) { asm volatile("s_waitcnt vmcnt(2)"); }
                  else      { asm volatile("s_waitcnt vmcnt(0)"); }
              },
              );
    }
#undef PHASE
#undef STG_A
#undef STG_B

    // ---- epilogue: gates + in-register chunk prefix scan ----
#pragma unroll
    for (int nf = 0; nf < 2; ++nf) {
        const int gcol = colbase + wc * 32 + nf * 16 + lr;
        const float brv = br[gcol];
        const float biv = bi[gcol];
        const float dec = decay[gcol];
#pragma unroll
        for (int half = 0; half < 2; ++half) {
            float Sp = 1.0f, Sh = 0.0f;
#pragma unroll
            for (int m4 = 0; m4 < 4; ++m4) {
                const int mi = half * 4 + m4;
                float av[4], gv[4];
#pragma unroll
                for (int rr = 0; rr < 4; ++rr) {
                    const int grow = rowbase + wr * 128 + mi * 16 + lg * 4 + rr;
                    const float zr = ar[mi][nf][rr] + brv;
                    const float zi = ai[mi][nf][rr] + biv;
                    const float rg = 1.0f / (1.0f + __expf(-zr));
                    const float ig = 1.0f / (1.0f + __expf(-zi));
                    av[rr] = __expf(-dec * rg);
                    const float sc = sqrtf(fmaxf(1.0f - av[rr] * av[rr], 0.0f));
                    gv[rr] = sc * (ig * bf2f(xb[(size_t)grow * D_ + gcol]));
                }
                // lane-local compose over 4 rows
                float lp = (av[0] * av[1]) * (av[2] * av[3]);
                float lh = gv[0];
                lh = av[1] * lh + gv[1];
                lh = av[2] * lh + gv[2];
                lh = av[3] * lh + gv[3];
                // ordered inclusive scan across lg (groups of 16 lanes)
                float cp = lp, ch = lh;
                {
                    const float pp = __shfl_up(cp, 16, 64);
                    const float ph = __shfl_up(ch, 16, 64);
                    if (lg >= 1) { ch = cp * ph + ch; cp = pp * cp; }
                }
                {
                    const float pp = __shfl_up(cp, 32, 64);
                    const float ph = __shfl_up(ch, 32, 64);
                    if (lg >= 2) { ch = cp * ph + ch; cp = pp * cp; }
                }
                // exclusive across lg
                float ep = __shfl_up(cp, 16, 64);
                float eh = __shfl_up(ch, 16, 64);
                if (lg == 0) { ep = 1.0f; eh = 0.0f; }
                // state before my 4 rows
                float wp = Sp * ep;
                float wh = ep * Sh + eh;
#pragma unroll
                for (int rr = 0; rr < 4; ++rr) {
                    wh = av[rr] * wh + gv[rr];
                    wp = wp * av[rr];
                    const int grow = rowbase + wr * 128 + mi * 16 + lg * 4 + rr;
                    ag[(size_t)grow * D_ + gcol] = pack2(wp, wh);
                }
                // advance S by the full 16-row block (inclusive at lg==3)
                const float fp3 = __shfl(cp, 48 + lr, 64);
                const float fh3 = __shfl(ch, 48 + lr, 64);
                Sh = fp3 * Sh + fh3;
                Sp = Sp * fp3;
            }
            if (lg == 0) {
                const int gc = (rowbase >> 6) + wr * 2 + half;   // global chunk id
                Pg[(size_t)gc * D_ + gcol] = Sp;
                Hg[(size_t)gc * D_ + gcol] = Sh;
            }
        }
    }
}

// ---------------------------------------------------------------- combine
__global__ __launch_bounds__(256) void combine(const float* __restrict__ P,
                                               const float* __restrict__ H,
                                               const float* __restrict__ h0,
                                               float* __restrict__ hstart,
                                               float* __restrict__ hT) {
    const int idx = blockIdx.x * 256 + threadIdx.x;   // [0, B*D)
    const int d = idx & (D_ - 1);
    const int b = idx >> 10;
    float h = h0[b * D_ + d];
    for (int c = 0; c < NC_; ++c) {
        const int o = (b * NC_ + c) * D_ + d;
        hstart[o] = h;
        h = P[o] * h + H[o];
    }
    hT[b * D_ + d] = h;
}

// ---------------------------------------------------------------- scan2: pointwise fixup
__global__ __launch_bounds__(256) void scan2(const uint4* __restrict__ ag4,
                                             const float4* __restrict__ hs4,
                                             float4* __restrict__ out4) {
    const int n = (BT_ * D_) / 4;
    const int stride = gridDim.x * 256;
    for (int i = blockIdx.x * 256 + threadIdx.x; i < n; i += stride) {
        const int d4 = i & (D_ / 4 - 1);     // 0..255
        const int row = i >> 8;               // b*T + t
        const int b = row >> 12;
        const int c = (row & (T_ - 1)) >> 6;
        const float4 hs = hs4[(size_t)(b * NC_ + c) * (D_ / 4) + d4];
        const uint4 v = ag4[i];
        float4 o;
        o.x = unp_hi(v.x) + unp_lo(v.x) * hs.x;
        o.y = unp_hi(v.y) + unp_lo(v.y) * hs.y;
        o.z = unp_hi(v.z) + unp_lo(v.z) * hs.z;
        o.w = unp_hi(v.w) + unp_lo(v.w) * hs.w;
        out4[i] = o;
    }
}

// ---------------------------------------------------------------- launch
extern "C" void kernel_launch(void* const* d_in, const int* in_sizes, int n_in,
                              void* d_out, int out_size, void* d_ws, size_t ws_size,
                              hipStream_t stream) {
    const float* x   = (const float*)d_in[0];
    const float* h0  = (const float*)d_in[1];
    const float* Wr  = (const float*)d_in[2];
    const float* br  = (const float*)d_in[3];
    const float* Wi  = (const float*)d_in[4];
    const float* bi  = (const float*)d_in[5];
    const float* lam = (const float*)d_in[6];
    float* out = (float*)d_out;

    char* ws = (char*)d_ws;
    unsigned short* xb  = (unsigned short*)ws; ws += (size_t)BT_ * D_ * 2;   // 33.5 MB
    unsigned short* wrb = (unsigned short*)ws; ws += (size_t)D_ * D_ * 2;    //  2 MB
    unsigned short* wib = (unsigned short*)ws; ws += (size_t)D_ * D_ * 2;    //  2 MB
    float* decay  = (float*)ws;  ws += (size_t)D_ * 4;                       //  4 KB
    u32* ag       = (u32*)ws;    ws += (size_t)BT_ * D_ * 4;                 // 67 MB
    float* Pg     = (float*)ws;  ws += (size_t)B_ * NC_ * D_ * 4;            //  1 MB
    float* Hg     = (float*)ws;  ws += (size_t)B_ * NC_ * D_ * 4;            //  1 MB
    float* hstart = (float*)ws;                                              //  1 MB

    prep_kernel<<<2048, 256, 0, stream>>>(
        (const float4*)x, (const float4*)Wr, (const float4*)Wi, lam,
        (ushort4*)xb, (ushort4*)wrb, (ushort4*)wib, decay);

    gemm_gates<<<512, 512, 0, stream>>>(
        xb, wrb, wib, br, bi, decay, ag, Pg, Hg);

    combine<<<(B_ * D_) / 256, 256, 0, stream>>>(Pg, Hg, h0, hstart, out + (size_t)BT_ * D_);

    scan2<<<2048, 256, 0, stream>>>((const uint4*)ag, (const float4*)hstart, (float4*)out);
}